// Round 17
// baseline (514.236 us; speedup 1.0000x reference)
//
#include <hip/hip_runtime.h>

#define T_TOK 8192
#define H_DIM 1024
#define F_DIM 4096
#define E_NUM 8

typedef __attribute__((ext_vector_type(8))) short short8;
typedef __attribute__((ext_vector_type(4))) float f32x4;

__device__ __forceinline__ unsigned short f2bf(float f) {
  unsigned int u = __float_as_uint(f);
  return (unsigned short)((u + 0x7fffu + ((u >> 16) & 1u)) >> 16);
}

__device__ __forceinline__ float bf2f(unsigned short u) {
  return __uint_as_float((unsigned int)u << 16);
}

// tanh-form gelu rewritten as v*sigmoid(2z): v / (1 + 2^(c1*v + c2*v^3)).
__device__ __forceinline__ float gelu_f(float v) {
  const float t1 = v * v;
  const float t2 = fmaf(-0.10294578f, t1, -2.30226510f);
  const float zz = t2 * v;
  const float e = __builtin_amdgcn_exp2f(zz);
  return v * __builtin_amdgcn_rcpf(1.0f + e);
}

__device__ __forceinline__ void gload16(const void* g, void* l) {
  __builtin_amdgcn_global_load_lds(
      (__attribute__((address_space(1))) const unsigned int*)(unsigned long long)g,
      (__attribute__((address_space(3))) unsigned int*)(unsigned int)(unsigned long long)l,
      16, 0, 0);
}

// ---------------- fused prep: logits (+x->bf16) AND both weight transposes ----------------
// blocks 0..2047: logits; blocks 2048..34815: transpose (16384 for W1, 16384 for W2)
__global__ __launch_bounds__(256) void k_prep(const float* __restrict__ W1,
                                              unsigned short* __restrict__ w1t,
                                              const float* __restrict__ W2,
                                              unsigned short* __restrict__ w2t,
                                              const float* __restrict__ x,
                                              const float* __restrict__ Wr,
                                              const float* __restrict__ br,
                                              double* __restrict__ ld,
                                              float* __restrict__ out_logits,
                                              unsigned short* __restrict__ xb) {
  __shared__ float tile[64][33];
  const int bid = blockIdx.x;
  if (bid < 2048) {
    // ---- logits body (identical math to prior k_logits) ----
    const int lane = threadIdx.x & 63;
    const int t = bid * 4 + (threadIdx.x >> 6);
    double acc[8] = {0, 0, 0, 0, 0, 0, 0, 0};
#pragma unroll
    for (int i = 0; i < 16; ++i) {
      const int h = i * 64 + lane;
      const float xv = x[(size_t)t * H_DIM + h];
      xb[(size_t)t * H_DIM + h] = f2bf(xv);
      const float4 wa = ((const float4*)Wr)[h * 2];
      const float4 wb = ((const float4*)Wr)[h * 2 + 1];
      acc[0] += (double)xv * wa.x; acc[1] += (double)xv * wa.y;
      acc[2] += (double)xv * wa.z; acc[3] += (double)xv * wa.w;
      acc[4] += (double)xv * wb.x; acc[5] += (double)xv * wb.y;
      acc[6] += (double)xv * wb.z; acc[7] += (double)xv * wb.w;
    }
#pragma unroll
    for (int e = 0; e < 8; ++e)
#pragma unroll
      for (int m = 32; m; m >>= 1) acc[e] += __shfl_xor(acc[e], m);
    if (lane == 0) {
#pragma unroll
      for (int e = 0; e < 8; ++e) {
        const double l = acc[e] + (double)br[e];
        ld[(size_t)t * 8 + e] = l;
        out_logits[(size_t)t * 8 + e] = (float)l;
      }
    }
    return;
  }
  // ---- transpose body ----
  const int idx = bid - 2048;
  const int part = idx >> 14;        // 0: W1, 1: W2
  const int rem = idx & 16383;
  const int e = rem >> 11;           // 0..7
  const int bl = rem & 2047;
  const float* in;
  unsigned short* out;
  int R, C, bx, byy;
  if (part == 0) {
    in = W1; out = w1t; R = H_DIM; C = F_DIM;
    bx = bl & 127; byy = bl >> 7;
  } else {
    in = W2; out = w2t; R = F_DIM; C = H_DIM;
    bx = bl & 31; byy = bl >> 5;
  }
  const size_t eoff = (size_t)e * R * C;
  const int c0 = bx * 32, r0 = byy * 64;
  const int tx = threadIdx.x & 31, ty = threadIdx.x >> 5;
#pragma unroll
  for (int i = 0; i < 8; ++i)
    tile[ty + i * 8][tx] = in[eoff + (size_t)(r0 + ty + i * 8) * C + (c0 + tx)];
  __syncthreads();
  const int ow = threadIdx.x & 63, oc = threadIdx.x >> 6;
#pragma unroll
  for (int i = 0; i < 8; ++i)
    out[eoff + (size_t)(c0 + oc + i * 4) * R + (r0 + ow)] = f2bf(tile[ow][oc + i * 4]);
}

// ---------------- router part 2: decisions + bucketing + slot map ----------------
__global__ __launch_bounds__(256) void k_decide(const double* __restrict__ ld,
                                                float* __restrict__ out_rw,
                                                float* __restrict__ out_disp,
                                                int* __restrict__ cnt,
                                                int* __restrict__ bidx,
                                                float* __restrict__ bgate,
                                                float* __restrict__ sums,
                                                int* __restrict__ slotmap) {
  __shared__ int hcnt[8];
  __shared__ int hbase[8];
  __shared__ float srw[8];
  __shared__ float sds[8];
  const int tloc = threadIdx.x;
  const int t = blockIdx.x * 256 + tloc;
  const int lane = tloc & 63;
  if (tloc < 8) { hcnt[tloc] = 0; srw[tloc] = 0.0f; sds[tloc] = 0.0f; }
  __syncthreads();

  double l[8];
#pragma unroll
  for (int e = 0; e < 8; ++e) l[e] = ld[(size_t)t * 8 + e];
  double mx = l[0];
#pragma unroll
  for (int e = 1; e < 8; ++e) mx = l[e] > mx ? l[e] : mx;
  double ex[8], se = 0.0;
#pragma unroll
  for (int e = 0; e < 8; ++e) { ex[e] = exp(l[e] - mx); se += ex[e]; }
  int i1 = 0;
#pragma unroll
  for (int e = 1; e < 8; ++e) if (l[e] > l[i1]) i1 = e;
  int i2 = (i1 == 0) ? 1 : 0;
#pragma unroll
  for (int e = 0; e < 8; ++e) if (e != i1 && l[e] > l[i2]) i2 = e;
  const double g1 = 1.0 / (1.0 + exp(l[i2] - l[i1]));
  const double g2 = 1.0 - g1;

  float rwv[8];
#pragma unroll
  for (int e = 0; e < 8; ++e) {
    rwv[e] = (float)(ex[e] / se);
    out_rw[(size_t)t * 8 + e] = rwv[e];
    out_disp[(size_t)t * 8 + e] = (e == i1) ? (float)g1 : (e == i2) ? (float)g2 : 0.0f;
  }
#pragma unroll
  for (int e = 0; e < 8; ++e) {
    float v = rwv[e];
#pragma unroll
    for (int m = 32; m; m >>= 1) v += __shfl_xor(v, m);
    if (lane == 0) atomicAdd(&srw[e], v);
  }
  atomicAdd(&sds[i1], (float)g1);
  atomicAdd(&sds[i2], (float)g2);

  const int loc1 = atomicAdd(&hcnt[i1], 1);
  const int loc2 = atomicAdd(&hcnt[i2], 1);
  __syncthreads();
  if (tloc < 8) hbase[tloc] = atomicAdd(&cnt[tloc], hcnt[tloc]);
  __syncthreads();
  const int s1 = hbase[i1] + loc1;
  const int s2 = hbase[i2] + loc2;
  bidx[i1 * T_TOK + s1] = t; bgate[i1 * T_TOK + s1] = (float)g1;
  bidx[i2 * T_TOK + s2] = t; bgate[i2 * T_TOK + s2] = (float)g2;
  slotmap[t * 2]     = (i1 << 16) | s1;
  slotmap[t * 2 + 1] = (i2 << 16) | s2;
  if (tloc < 8) {
    atomicAdd(&sums[tloc], srw[tloc]);
    atomicAdd(&sums[8 + tloc], sds[tloc]);
  }
}

// ---------------- prefix + aux loss + bucket-pad fill ----------------
__global__ __launch_bounds__(256) void k_prefix_aux(const int* __restrict__ cnt,
                                                    int* __restrict__ abase,
                                                    const float* __restrict__ sums,
                                                    float* __restrict__ out_aux,
                                                    int* __restrict__ bidx,
                                                    float* __restrict__ bgate) {
  int c[8], pc[8];
#pragma unroll
  for (int e = 0; e < 8; ++e) { c[e] = cnt[e]; pc[e] = (c[e] + 127) & ~127; }
  if (threadIdx.x == 0) {
    int base = 0;
#pragma unroll
    for (int e = 0; e < 8; ++e) { abase[e] = base; base += pc[e]; }
    abase[8] = base;
    double aux = 0.0;
#pragma unroll
    for (int e = 0; e < 8; ++e) aux += ((double)sums[e] / 8192.0) * ((double)sums[8 + e] / 8192.0);
    *out_aux = (float)(aux * 8.0);
  }
#pragma unroll
  for (int e = 0; e < 8; ++e) {
    for (int s = c[e] + threadIdx.x; s < pc[e]; s += 256) {
      bidx[e * T_TOK + s] = 0;
      bgate[e * T_TOK + s] = 0.0f;
    }
  }
}

// ---------------- GEMM1: abuf = gelu(g*(x@W1)+b1) — m97-style 128x128, BK=32, 4 waves ----------------
__global__ __launch_bounds__(256) void k_gemm1(
    const unsigned short* __restrict__ xb, const unsigned short* __restrict__ w1t,
    const float* __restrict__ b1, const int* __restrict__ bidx,
    const float* __restrict__ bgate, const int* __restrict__ abase,
    unsigned short* __restrict__ abuf) {
  const int e = blockIdx.z, by = blockIdx.y, bx = blockIdx.x;
  const int pb = abase[e];
  const int pcnt = abase[e + 1] - pb;
  if (by * 128 >= pcnt) return;
  const int tid = threadIdx.x, wid = tid >> 6, lane = tid & 63;
  const int r0 = tid >> 2, kseg = tid & 3;
  const int t0 = bidx[e * T_TOK + by * 128 + r0];
  const int t1 = bidx[e * T_TOK + by * 128 + 64 + r0];
  const char* gA0 = (const char*)(xb + (size_t)t0 * H_DIM + kseg * 8);
  const char* gA1 = (const char*)(xb + (size_t)t1 * H_DIM + kseg * 8);
  const char* gB0 = (const char*)(w1t + ((size_t)e * F_DIM + bx * 128 + r0) * H_DIM + kseg * 8);
  const char* gB1 = gB0 + (size_t)64 * H_DIM * 2;
  __shared__ __align__(16) char smem[2][16384];
  f32x4 acc[4][4] = {};
  const int wm = wid >> 1, wn = wid & 1;
  const int aoff = (wm * 64 + (lane & 15)) * 64 + (lane >> 4) * 16;
  const int boff = 8192 + (wn * 64 + (lane & 15)) * 64 + (lane >> 4) * 16;
  {
    char* s = smem[0] + wid * 1024;
    gload16(gA0, s); gload16(gA1, s + 4096);
    gload16(gB0, s + 8192); gload16(gB1, s + 12288);
  }
  __syncthreads();
  for (int kt = 0; kt < 32; ++kt) {
    const int cur = kt & 1;
    if (kt + 1 < 32) {
      const int koff = (kt + 1) * 64;  // 32 bf16 per k-step
      char* s = smem[cur ^ 1] + wid * 1024;
      gload16(gA0 + koff, s); gload16(gA1 + koff, s + 4096);
      gload16(gB0 + koff, s + 8192); gload16(gB1 + koff, s + 12288);
    }
    short8 af[4], bf[4];
#pragma unroll
    for (int mi = 0; mi < 4; ++mi) af[mi] = *(const short8*)(smem[cur] + aoff + mi * 1024);
#pragma unroll
    for (int ni = 0; ni < 4; ++ni) bf[ni] = *(const short8*)(smem[cur] + boff + ni * 1024);
#pragma unroll
    for (int mi = 0; mi < 4; ++mi)
#pragma unroll
      for (int ni = 0; ni < 4; ++ni)
        acc[mi][ni] = __builtin_amdgcn_mfma_f32_16x16x32_bf16(af[mi], bf[ni], acc[mi][ni], 0, 0, 0);
    __syncthreads();
  }
  // epilogue: gelu -> per-wave 8KB LDS repack (XOR swizzle) -> coalesced 16B stores
  const int lcol = lane & 15, lr4 = (lane >> 4) * 4;
  const int gcol0 = bx * 128 + wn * 64;
  float b1v[4];
#pragma unroll
  for (int ni = 0; ni < 4; ++ni) b1v[ni] = b1[(size_t)e * F_DIM + gcol0 + ni * 16 + lcol];
  const float* bg_e = bgate + e * T_TOK + by * 128 + wm * 64;
  char* wsm = (char*)smem + wid * 8192;  // wave-private 64 rows x 128 B
#pragma unroll
  for (int mi = 0; mi < 4; ++mi) {
#pragma unroll
    for (int r = 0; r < 4; ++r) {
      const int wrow = mi * 16 + lr4 + r;  // 0..63 local row
      const float gt = (by * 128 + wm * 64 + wrow < pcnt) ? bg_e[wrow] : 0.0f;
#pragma unroll
      for (int ni = 0; ni < 4; ++ni) {
        const float v = fmaf(gt, acc[mi][ni][r], b1v[ni]);
        const int col2 = (ni * 16 + lcol) * 2;
        *(unsigned short*)(wsm + wrow * 128 + (col2 ^ ((wrow & 7) << 4))) = f2bf(gelu_f(v));
      }
    }
  }
#pragma unroll
  for (int r = 0; r < 8; ++r) {
    const int row = r * 8 + (lane >> 3);               // 0..63 local row
    const int chunk = (lane & 7) ^ (row & 7);
    const int grow = by * 128 + wm * 64 + row;
    if (grow < pcnt) {
      short8 vv = *(const short8*)(wsm + row * 128 + chunk * 16);
      *(short8*)(abuf + (size_t)(pb + grow) * F_DIM + gcol0 + (lane & 7) * 8) = vv;
    }
  }
}

// ======================= 256x256 8-phase GEMM template pieces (gemm2) =======================
#define MFMA_Q(qm_, qn_, Bset_)                                                        \
  do {                                                                                 \
    _Pragma("unroll") for (int kh = 0; kh < 2; ++kh)                                   \
    _Pragma("unroll") for (int mi = 0; mi < 4; ++mi)                                   \
    _Pragma("unroll") for (int ni = 0; ni < 2; ++ni)                                   \
      acc[(qm_)*4 + mi][(qn_)*2 + ni] = __builtin_amdgcn_mfma_f32_16x16x32_bf16(       \
          Areg[mi][kh], Bset_[ni][kh], acc[(qm_)*4 + mi][(qn_)*2 + ni], 0, 0, 0);      \
  } while (0)

#define LOAD_A(mh_)                                                                    \
  do {                                                                                 \
    const char* Ab = smem + slot * 65536 + (mh_)*16384;                                \
    _Pragma("unroll") for (int mi = 0; mi < 4; ++mi) {                                 \
      Areg[mi][0] = *(const short8*)(Ab + mi * 2048 + aoffk0);                         \
      Areg[mi][1] = *(const short8*)(Ab + mi * 2048 + aoffk1);                         \
    }                                                                                  \
  } while (0)

#define LOAD_B(set_, nh_)                                                              \
  do {                                                                                 \
    const char* Bb = smem + slot * 65536 + 32768 + (nh_)*16384;                        \
    _Pragma("unroll") for (int ni = 0; ni < 2; ++ni) {                                 \
      set_[ni][0] = *(const short8*)(Bb + ni * 2048 + boffk0);                         \
      set_[ni][1] = *(const short8*)(Bb + ni * 2048 + boffk1);                         \
    }                                                                                  \
  } while (0)

#define PHASE_TAIL(MFMA_STMT)                                                          \
  __builtin_amdgcn_s_barrier();                                                        \
  __builtin_amdgcn_s_setprio(1);                                                       \
  MFMA_STMT;                                                                           \
  __builtin_amdgcn_s_setprio(0);                                                       \
  __builtin_amdgcn_s_barrier();

// ---------------- GEMM2: eout[ks][slot] = g * (abuf @ W2(Khalf) + b2?), K-split, bf16 out ----------------
__global__ __launch_bounds__(512, 2) void k_gemm2(
    const unsigned short* __restrict__ abuf, const unsigned short* __restrict__ w2t,
    const float* __restrict__ b2, const float* __restrict__ bgate,
    const int* __restrict__ abase, unsigned short* __restrict__ eout_a,
    unsigned short* __restrict__ eout_b, int split) {
  const int ez = blockIdx.z;
  const int e = ez & 7, ks = ez >> 3;
  const int by = blockIdx.y, bx = blockIdx.x;
  const int pb = abase[e], pcnt = abase[e + 1] - pb;
  if (by * 256 >= pcnt) return;
  const int g0 = ks * 32;
  const int gend = split ? (g0 + 32) : 64;
  unsigned short* eo = ks ? eout_b : eout_a;
  __shared__ char smem[131072];
  const int tid = threadIdx.x, wid = tid >> 6, lane = tid & 63;
  const int wr = wid >> 2, wc = wid & 3;
  const int rr0 = tid >> 3;
  const int kbyte = ((tid & 7) ^ (rr0 & 7)) * 16;
  const int d0 = tid * 16, d1 = d0 + 8192;
  const int aoffk0 = (wr * 64 + (lane & 15)) * 128 + (((lane >> 4) ^ (lane & 7)) * 16);
  const int aoffk1 = aoffk0 ^ 64;
  const int boffk0 = (wc * 32 + (lane & 15)) * 128 + (((lane >> 4) ^ (lane & 7)) * 16);
  const int boffk1 = boffk0 ^ 64;

  const char* Abase = (const char*)(abuf + (size_t)(pb + by * 256) * F_DIM);
  const int brB0 = ((rr0 >> 5) * 64 + (rr0 & 31));
  const char* Bbase = (const char*)(w2t + (size_t)e * H_DIM * F_DIM + (size_t)(bx * 256) * F_DIM);

#define G2_STAGE_A(g_, mh_)                                                            \
  do {                                                                                 \
    const char* s0 = Abase + (size_t)((mh_)*64 + rr0) * 8192 + (g_)*128 + kbyte;       \
    const char* s1 = Abase + (size_t)(128 + (mh_)*64 + rr0) * 8192 + (g_)*128 + kbyte; \
    char* dst = smem + (((g_)&1) * 65536) + (mh_)*16384;                               \
    gload16(s0, dst + d0); gload16(s1, dst + d1);                                      \
  } while (0)

#define G2_STAGE_B(g_, nh_)                                                            \
  do {                                                                                 \
    const char* s0 = Bbase + (size_t)(brB0 + (nh_)*32) * 8192 + (g_)*128 + kbyte;      \
    const char* s1 = Bbase + (size_t)(brB0 + 128 + (nh_)*32) * 8192 + (g_)*128 + kbyte;\
    char* dst = smem + (((g_)&1) * 65536) + 32768 + (nh_)*16384;                       \
    gload16(s0, dst + d0); gload16(s1, dst + d1);                                      \
  } while (0)

  f32x4 acc[8][4] = {};
  short8 Areg[4][2], B0reg[2][2], B1reg[2][2];

  G2_STAGE_A(g0, 0); G2_STAGE_B(g0, 1); G2_STAGE_A(g0, 1); G2_STAGE_B(g0, 0);
  G2_STAGE_A(g0 + 1, 0); G2_STAGE_B(g0 + 1, 1); G2_STAGE_A(g0 + 1, 1);
  asm volatile("s_waitcnt vmcnt(6)" ::: "memory");
  __builtin_amdgcn_sched_barrier(0);
  __builtin_amdgcn_s_barrier();

  for (int g = g0; g < gend; ++g) {
    const int slot = g & 1;
    LOAD_A(0); LOAD_B(B0reg, 0);
    if (g + 1 < gend) G2_STAGE_B(g + 1, 0);
    PHASE_TAIL(MFMA_Q(0, 0, B0reg));
    LOAD_B(B1reg, 1);
    if (g + 2 < gend) G2_STAGE_A(g + 2, 0);
    PHASE_TAIL(MFMA_Q(0, 1, B1reg));
    LOAD_A(1);
    if (g + 2 < gend) G2_STAGE_B(g + 2, 1);
    PHASE_TAIL(MFMA_Q(1, 1, B1reg));
    if (g + 2 < gend) {
      G2_STAGE_A(g + 2, 1);
      asm volatile("s_waitcnt vmcnt(6)" ::: "memory");
    } else if (g + 1 < gend) {
      asm volatile("s_waitcnt vmcnt(0)" ::: "memory");
    }
    __builtin_amdgcn_sched_barrier(0);
    PHASE_TAIL(MFMA_Q(1, 0, B0reg));
  }

  const int lcol = lane & 15;
  const int gcol0 = bx * 256 + wc * 64;
  float b2v[4];
#pragma unroll
  for (int n = 0; n < 4; ++n)
    b2v[n] = (ks == 0) ? b2[(size_t)e * H_DIM + gcol0 + n * 16 + lcol] : 0.0f;
  const float* bg_e = bgate + e * T_TOK;
#pragma unroll
  for (int m = 0; m < 8; ++m) {
    const int rl = wr * 128 + m * 16 + (lane >> 4) * 4;
#pragma unroll
    for (int j = 0; j < 4; ++j) {
      const int gm = by * 256 + rl + j;
      if (gm < pcnt) {
        const float gt = bg_e[gm];
        unsigned short* orow = eo + (size_t)(pb + gm) * H_DIM + gcol0;
#pragma unroll
        for (int n = 0; n < 4; ++n)
          orow[n * 16 + lcol] = f2bf((acc[m][n][j] + b2v[n]) * gt);
      }
    }
  }
#undef G2_STAGE_A
#undef G2_STAGE_B
}

// ---------------- combine: out[t] = sum of this token's slot rows (2 or 4), bf16 in ----------------
__global__ __launch_bounds__(256) void k_combine(const unsigned short* __restrict__ ea,
                                                 const unsigned short* __restrict__ eb,
                                                 const int* __restrict__ slotmap,
                                                 const int* __restrict__ abase,
                                                 float* __restrict__ outf, int split) {
  const int t = blockIdx.x;
  const int c = threadIdx.x;
  const int v0 = slotmap[t * 2], v1 = slotmap[t * 2 + 1];
  const size_t row0 = (size_t)(abase[v0 >> 16] + (v0 & 0xffff)) * H_DIM;
  const size_t row1 = (size_t)(abase[v1 >> 16] + (v1 & 0xffff)) * H_DIM;
  uint2 a = ((const uint2*)(ea + row0))[c];
  uint2 b = ((const uint2*)(ea + row1))[c];
  float r0 = bf2f(a.x & 0xffff) + bf2f(b.x & 0xffff);
  float r1 = bf2f(a.x >> 16)    + bf2f(b.x >> 16);
  float r2 = bf2f(a.y & 0xffff) + bf2f(b.y & 0xffff);
  float r3 = bf2f(a.y >> 16)    + bf2f(b.y >> 16);
  if (split) {
    uint2 p = ((const uint2*)(eb + row0))[c];
    uint2 q = ((const uint2*)(eb + row1))[c];
    r0 += bf2f(p.x & 0xffff) + bf2f(q.x & 0xffff);
    r1 += bf2f(p.x >> 16)    + bf2f(q.x >> 16);
    r2 += bf2f(p.y & 0xffff) + bf2f(q.y & 0xffff);
    r3 += bf2f(p.y >> 16)    + bf2f(q.y >> 16);
  }
  ((float4*)outf)[(size_t)t * 256 + c] = make_float4(r0, r1, r2, r3);
}

extern "C" void kernel_launch(void* const* d_in, const int* in_sizes, int n_in,
                              void* d_out, int out_size, void* d_ws, size_t ws_size,
                              hipStream_t stream) {
  const float* x  = (const float*)d_in[0];
  const float* Wr = (const float*)d_in[1];
  const float* br = (const float*)d_in[2];
  const float* W1 = (const float*)d_in[3];
  const float* b1 = (const float*)d_in[4];
  const float* W2 = (const float*)d_in[5];
  const float* b2 = (const float*)d_in[6];
  float* out = (float*)d_out;
  float* out_final  = out;                 // 8388608
  float* out_rw     = out + 8388608;       // 65536
  float* out_disp   = out_rw + 65536;      // 65536
  float* out_aux    = out_disp + 65536;    // 1
  float* out_logits = out_aux + 1;         // 65536

  char* ws = (char*)d_ws;
  unsigned short* xb   = (unsigned short*)(ws);                 // 16,777,216 B (dead after gemm1)
  unsigned short* w1t  = (unsigned short*)(ws + 16777216);      // 67,108,864 B (dead after gemm1)
  unsigned short* w2t  = (unsigned short*)(ws + 83886080);      // 67,108,864 B
  unsigned short* abuf = (unsigned short*)(ws + 150994944);     // 142,606,336 B (17408 rows)
  int*    bidx  = (int*)(ws + 293601280);                       // 262,144 B
  float*  bgate = (float*)(ws + 293863424);                     // 262,144 B
  int*    cnt   = (int*)(ws + 294125568);                       // 64 B
  int*    abase = (int*)(ws + 294125632);                       // 64 B
  float*  sums  = (float*)(ws + 294125696);                     // 64 B
  double* ld    = (double*)(ws + 294125824);                    // 524,288 B
  int*    slotmap = (int*)(ws + 294650112);                     // 65,536 B
  unsigned short* eout_a = (unsigned short*)(ws);               // 35.7 MB bf16, reuses xb+w1t
  unsigned short* eout_b = (unsigned short*)(ws + 35651584);    // 35.7 MB bf16, still inside xb+w1t

  const int split = 1;

  // single memset covers cnt(64) + abase(64) + sums(64)
  hipMemsetAsync(cnt, 0, 192, stream);

  k_prep<<<34816, 256, 0, stream>>>(W1, w1t, W2, w2t, x, Wr, br, ld, out_logits, xb);
  k_decide<<<32, 256, 0, stream>>>(ld, out_rw, out_disp, cnt, bidx, bgate, sums, slotmap);
  k_prefix_aux<<<1, 256, 0, stream>>>(cnt, abase, sums, out_aux, bidx, bgate);
  k_gemm1<<<dim3(32, 24, 8), 256, 0, stream>>>(xb, w1t, b1, bidx, bgate, abase, abuf);
  k_gemm2<<<dim3(4, 32, 16), 512, 0, stream>>>(abuf, w2t, b2, bgate, abase, eout_a, eout_b, split);
  k_combine<<<8192, 256, 0, stream>>>(eout_a, eout_b, slotmap, abase, out_final, split);
}

// Round 18
// 510.958 us; speedup vs baseline: 1.0064x; 1.0064x over previous
//
#include <hip/hip_runtime.h>

#define T_TOK 8192
#define H_DIM 1024
#define F_DIM 4096
#define E_NUM 8

typedef __attribute__((ext_vector_type(8))) short short8;
typedef __attribute__((ext_vector_type(4))) float f32x4;

__device__ __forceinline__ unsigned short f2bf(float f) {
  unsigned int u = __float_as_uint(f);
  return (unsigned short)((u + 0x7fffu + ((u >> 16) & 1u)) >> 16);
}

__device__ __forceinline__ float bf2f(unsigned short u) {
  return __uint_as_float((unsigned int)u << 16);
}

// tanh-form gelu rewritten as v*sigmoid(2z): v / (1 + 2^(c1*v + c2*v^3)).
__device__ __forceinline__ float gelu_f(float v) {
  const float t1 = v * v;
  const float t2 = fmaf(-0.10294578f, t1, -2.30226510f);
  const float zz = t2 * v;
  const float e = __builtin_amdgcn_exp2f(zz);
  return v * __builtin_amdgcn_rcpf(1.0f + e);
}

__device__ __forceinline__ void gload16(const void* g, void* l) {
  __builtin_amdgcn_global_load_lds(
      (__attribute__((address_space(1))) const unsigned int*)(unsigned long long)g,
      (__attribute__((address_space(3))) unsigned int*)(unsigned int)(unsigned long long)l,
      16, 0, 0);
}

// ---------------- prep: transpose+convert BOTH weights (one launch) ----------------
__global__ __launch_bounds__(256) void k_transpose_both(const float* __restrict__ W1,
                                                        unsigned short* __restrict__ w1t,
                                                        const float* __restrict__ W2,
                                                        unsigned short* __restrict__ w2t) {
  __shared__ float tile[64][33];
  const float* in;
  unsigned short* out;
  int R, C, bx, byy;
  if (blockIdx.y == 0) {
    in = W1; out = w1t; R = H_DIM; C = F_DIM;
    bx = blockIdx.x & 127; byy = blockIdx.x >> 7;   // 128 x 16 tiles
  } else {
    in = W2; out = w2t; R = F_DIM; C = H_DIM;
    bx = blockIdx.x & 31; byy = blockIdx.x >> 5;    // 32 x 64 tiles
  }
  const size_t eoff = (size_t)blockIdx.z * R * C;
  const int c0 = bx * 32, r0 = byy * 64;
  const int tx = threadIdx.x & 31, ty = threadIdx.x >> 5;
#pragma unroll
  for (int i = 0; i < 8; ++i)
    tile[ty + i * 8][tx] = in[eoff + (size_t)(r0 + ty + i * 8) * C + (c0 + tx)];
  __syncthreads();
  const int ow = threadIdx.x & 63, oc = threadIdx.x >> 6;
#pragma unroll
  for (int i = 0; i < 8; ++i)
    out[eoff + (size_t)(c0 + oc + i * 4) * R + (r0 + ow)] = f2bf(tile[ow][oc + i * 4]);
}

// ---------------- router part 1: logits (+ fused x -> bf16 convert) ----------------
__global__ __launch_bounds__(256) void k_logits(const float* __restrict__ x,
                                                const float* __restrict__ Wr,
                                                const float* __restrict__ br,
                                                double* __restrict__ ld,
                                                float* __restrict__ out_logits,
                                                unsigned short* __restrict__ xb) {
  const int lane = threadIdx.x & 63;
  const int t = blockIdx.x * 4 + (threadIdx.x >> 6);
  double acc[8] = {0, 0, 0, 0, 0, 0, 0, 0};
#pragma unroll
  for (int i = 0; i < 16; ++i) {
    const int h = i * 64 + lane;
    const float xv = x[(size_t)t * H_DIM + h];
    xb[(size_t)t * H_DIM + h] = f2bf(xv);
    const float4 wa = ((const float4*)Wr)[h * 2];
    const float4 wb = ((const float4*)Wr)[h * 2 + 1];
    acc[0] += (double)xv * wa.x; acc[1] += (double)xv * wa.y;
    acc[2] += (double)xv * wa.z; acc[3] += (double)xv * wa.w;
    acc[4] += (double)xv * wb.x; acc[5] += (double)xv * wb.y;
    acc[6] += (double)xv * wb.z; acc[7] += (double)xv * wb.w;
  }
#pragma unroll
  for (int e = 0; e < 8; ++e)
#pragma unroll
    for (int m = 32; m; m >>= 1) acc[e] += __shfl_xor(acc[e], m);
  if (lane == 0) {
#pragma unroll
    for (int e = 0; e < 8; ++e) {
      const double l = acc[e] + (double)br[e];
      ld[(size_t)t * 8 + e] = l;
      out_logits[(size_t)t * 8 + e] = (float)l;
    }
  }
}

// ---------------- router part 2: decisions + bucketing + slot map ----------------
__global__ __launch_bounds__(256) void k_decide(const double* __restrict__ ld,
                                                float* __restrict__ out_rw,
                                                float* __restrict__ out_disp,
                                                int* __restrict__ cnt,
                                                int* __restrict__ bidx,
                                                float* __restrict__ bgate,
                                                float* __restrict__ sums,
                                                int* __restrict__ slotmap) {
  __shared__ int hcnt[8];
  __shared__ int hbase[8];
  __shared__ float srw[8];
  __shared__ float sds[8];
  const int tloc = threadIdx.x;
  const int t = blockIdx.x * 256 + tloc;
  const int lane = tloc & 63;
  if (tloc < 8) { hcnt[tloc] = 0; srw[tloc] = 0.0f; sds[tloc] = 0.0f; }
  __syncthreads();

  double l[8];
#pragma unroll
  for (int e = 0; e < 8; ++e) l[e] = ld[(size_t)t * 8 + e];
  double mx = l[0];
#pragma unroll
  for (int e = 1; e < 8; ++e) mx = l[e] > mx ? l[e] : mx;
  double ex[8], se = 0.0;
#pragma unroll
  for (int e = 0; e < 8; ++e) { ex[e] = exp(l[e] - mx); se += ex[e]; }
  int i1 = 0;
#pragma unroll
  for (int e = 1; e < 8; ++e) if (l[e] > l[i1]) i1 = e;
  int i2 = (i1 == 0) ? 1 : 0;
#pragma unroll
  for (int e = 0; e < 8; ++e) if (e != i1 && l[e] > l[i2]) i2 = e;
  const double g1 = 1.0 / (1.0 + exp(l[i2] - l[i1]));
  const double g2 = 1.0 - g1;

  float rwv[8];
#pragma unroll
  for (int e = 0; e < 8; ++e) {
    rwv[e] = (float)(ex[e] / se);
    out_rw[(size_t)t * 8 + e] = rwv[e];
    out_disp[(size_t)t * 8 + e] = (e == i1) ? (float)g1 : (e == i2) ? (float)g2 : 0.0f;
  }
#pragma unroll
  for (int e = 0; e < 8; ++e) {
    float v = rwv[e];
#pragma unroll
    for (int m = 32; m; m >>= 1) v += __shfl_xor(v, m);
    if (lane == 0) atomicAdd(&srw[e], v);
  }
  atomicAdd(&sds[i1], (float)g1);
  atomicAdd(&sds[i2], (float)g2);

  const int loc1 = atomicAdd(&hcnt[i1], 1);
  const int loc2 = atomicAdd(&hcnt[i2], 1);
  __syncthreads();
  if (tloc < 8) hbase[tloc] = atomicAdd(&cnt[tloc], hcnt[tloc]);
  __syncthreads();
  const int s1 = hbase[i1] + loc1;
  const int s2 = hbase[i2] + loc2;
  bidx[i1 * T_TOK + s1] = t; bgate[i1 * T_TOK + s1] = (float)g1;
  bidx[i2 * T_TOK + s2] = t; bgate[i2 * T_TOK + s2] = (float)g2;
  slotmap[t * 2]     = (i1 << 16) | s1;
  slotmap[t * 2 + 1] = (i2 << 16) | s2;
  if (tloc < 8) {
    atomicAdd(&sums[tloc], srw[tloc]);
    atomicAdd(&sums[8 + tloc], sds[tloc]);
  }
}

// ---------------- prefix + aux loss + bucket-pad fill ----------------
__global__ __launch_bounds__(256) void k_prefix_aux(const int* __restrict__ cnt,
                                                    int* __restrict__ abase,
                                                    const float* __restrict__ sums,
                                                    float* __restrict__ out_aux,
                                                    int* __restrict__ bidx,
                                                    float* __restrict__ bgate) {
  int c[8], pc[8];
#pragma unroll
  for (int e = 0; e < 8; ++e) { c[e] = cnt[e]; pc[e] = (c[e] + 127) & ~127; }
  if (threadIdx.x == 0) {
    int base = 0;
#pragma unroll
    for (int e = 0; e < 8; ++e) { abase[e] = base; base += pc[e]; }
    abase[8] = base;
    double aux = 0.0;
#pragma unroll
    for (int e = 0; e < 8; ++e) aux += ((double)sums[e] / 8192.0) * ((double)sums[8 + e] / 8192.0);
    *out_aux = (float)(aux * 8.0);
  }
#pragma unroll
  for (int e = 0; e < 8; ++e) {
    for (int s = c[e] + threadIdx.x; s < pc[e]; s += 256) {
      bidx[e * T_TOK + s] = 0;
      bgate[e * T_TOK + s] = 0.0f;
    }
  }
}

// ---------------- GEMM1: abuf = gelu(g*(x@W1)+b1) — m97-style 128x128, BK=32, 4 waves ----------------
__global__ __launch_bounds__(256) void k_gemm1(
    const unsigned short* __restrict__ xb, const unsigned short* __restrict__ w1t,
    const float* __restrict__ b1, const int* __restrict__ bidx,
    const float* __restrict__ bgate, const int* __restrict__ abase,
    unsigned short* __restrict__ abuf) {
  const int e = blockIdx.z, by = blockIdx.y, bx = blockIdx.x;
  const int pb = abase[e];
  const int pcnt = abase[e + 1] - pb;
  if (by * 128 >= pcnt) return;
  const int tid = threadIdx.x, wid = tid >> 6, lane = tid & 63;
  const int r0 = tid >> 2, kseg = tid & 3;
  const int t0 = bidx[e * T_TOK + by * 128 + r0];
  const int t1 = bidx[e * T_TOK + by * 128 + 64 + r0];
  const char* gA0 = (const char*)(xb + (size_t)t0 * H_DIM + kseg * 8);
  const char* gA1 = (const char*)(xb + (size_t)t1 * H_DIM + kseg * 8);
  const char* gB0 = (const char*)(w1t + ((size_t)e * F_DIM + bx * 128 + r0) * H_DIM + kseg * 8);
  const char* gB1 = gB0 + (size_t)64 * H_DIM * 2;
  __shared__ __align__(16) char smem[2][16384];
  f32x4 acc[4][4] = {};
  const int wm = wid >> 1, wn = wid & 1;
  const int aoff = (wm * 64 + (lane & 15)) * 64 + (lane >> 4) * 16;
  const int boff = 8192 + (wn * 64 + (lane & 15)) * 64 + (lane >> 4) * 16;
  {
    char* s = smem[0] + wid * 1024;
    gload16(gA0, s); gload16(gA1, s + 4096);
    gload16(gB0, s + 8192); gload16(gB1, s + 12288);
  }
  __syncthreads();
  for (int kt = 0; kt < 32; ++kt) {
    const int cur = kt & 1;
    if (kt + 1 < 32) {
      const int koff = (kt + 1) * 64;  // 32 bf16 per k-step
      char* s = smem[cur ^ 1] + wid * 1024;
      gload16(gA0 + koff, s); gload16(gA1 + koff, s + 4096);
      gload16(gB0 + koff, s + 8192); gload16(gB1 + koff, s + 12288);
    }
    short8 af[4], bf[4];
#pragma unroll
    for (int mi = 0; mi < 4; ++mi) af[mi] = *(const short8*)(smem[cur] + aoff + mi * 1024);
#pragma unroll
    for (int ni = 0; ni < 4; ++ni) bf[ni] = *(const short8*)(smem[cur] + boff + ni * 1024);
#pragma unroll
    for (int mi = 0; mi < 4; ++mi)
#pragma unroll
      for (int ni = 0; ni < 4; ++ni)
        acc[mi][ni] = __builtin_amdgcn_mfma_f32_16x16x32_bf16(af[mi], bf[ni], acc[mi][ni], 0, 0, 0);
    __syncthreads();
  }
  // epilogue: gelu -> per-wave 8KB LDS repack (XOR swizzle) -> coalesced 16B stores
  const int lcol = lane & 15, lr4 = (lane >> 4) * 4;
  const int gcol0 = bx * 128 + wn * 64;
  float b1v[4];
#pragma unroll
  for (int ni = 0; ni < 4; ++ni) b1v[ni] = b1[(size_t)e * F_DIM + gcol0 + ni * 16 + lcol];
  const float* bg_e = bgate + e * T_TOK + by * 128 + wm * 64;
  char* wsm = (char*)smem + wid * 8192;  // wave-private 64 rows x 128 B
#pragma unroll
  for (int mi = 0; mi < 4; ++mi) {
#pragma unroll
    for (int r = 0; r < 4; ++r) {
      const int wrow = mi * 16 + lr4 + r;  // 0..63 local row
      const float gt = (by * 128 + wm * 64 + wrow < pcnt) ? bg_e[wrow] : 0.0f;
#pragma unroll
      for (int ni = 0; ni < 4; ++ni) {
        const float v = fmaf(gt, acc[mi][ni][r], b1v[ni]);
        const int col2 = (ni * 16 + lcol) * 2;
        *(unsigned short*)(wsm + wrow * 128 + (col2 ^ ((wrow & 7) << 4))) = f2bf(gelu_f(v));
      }
    }
  }
#pragma unroll
  for (int r = 0; r < 8; ++r) {
    const int row = r * 8 + (lane >> 3);               // 0..63 local row
    const int chunk = (lane & 7) ^ (row & 7);
    const int grow = by * 128 + wm * 64 + row;
    if (grow < pcnt) {
      short8 vv = *(const short8*)(wsm + row * 128 + chunk * 16);
      *(short8*)(abuf + (size_t)(pb + grow) * F_DIM + gcol0 + (lane & 7) * 8) = vv;
    }
  }
}

// ======================= 256x256 8-phase GEMM template pieces (gemm2) =======================
#define MFMA_Q(qm_, qn_, Bset_)                                                        \
  do {                                                                                 \
    _Pragma("unroll") for (int kh = 0; kh < 2; ++kh)                                   \
    _Pragma("unroll") for (int mi = 0; mi < 4; ++mi)                                   \
    _Pragma("unroll") for (int ni = 0; ni < 2; ++ni)                                   \
      acc[(qm_)*4 + mi][(qn_)*2 + ni] = __builtin_amdgcn_mfma_f32_16x16x32_bf16(       \
          Areg[mi][kh], Bset_[ni][kh], acc[(qm_)*4 + mi][(qn_)*2 + ni], 0, 0, 0);      \
  } while (0)

#define LOAD_A(mh_)                                                                    \
  do {                                                                                 \
    const char* Ab = smem + slot * 65536 + (mh_)*16384;                                \
    _Pragma("unroll") for (int mi = 0; mi < 4; ++mi) {                                 \
      Areg[mi][0] = *(const short8*)(Ab + mi * 2048 + aoffk0);                         \
      Areg[mi][1] = *(const short8*)(Ab + mi * 2048 + aoffk1);                         \
    }                                                                                  \
  } while (0)

#define LOAD_B(set_, nh_)                                                              \
  do {                                                                                 \
    const char* Bb = smem + slot * 65536 + 32768 + (nh_)*16384;                        \
    _Pragma("unroll") for (int ni = 0; ni < 2; ++ni) {                                 \
      set_[ni][0] = *(const short8*)(Bb + ni * 2048 + boffk0);                         \
      set_[ni][1] = *(const short8*)(Bb + ni * 2048 + boffk1);                         \
    }                                                                                  \
  } while (0)

#define PHASE_TAIL(MFMA_STMT)                                                          \
  __builtin_amdgcn_s_barrier();                                                        \
  __builtin_amdgcn_s_setprio(1);                                                       \
  MFMA_STMT;                                                                           \
  __builtin_amdgcn_s_setprio(0);                                                       \
  __builtin_amdgcn_s_barrier();

// ---------------- GEMM2: eout[ks][slot] = g * (abuf @ W2(Khalf) + b2?), K-split, bf16 out ----------------
__global__ __launch_bounds__(512, 2) void k_gemm2(
    const unsigned short* __restrict__ abuf, const unsigned short* __restrict__ w2t,
    const float* __restrict__ b2, const float* __restrict__ bgate,
    const int* __restrict__ abase, unsigned short* __restrict__ eout_a,
    unsigned short* __restrict__ eout_b, int split) {
  const int ez = blockIdx.z;
  const int e = ez & 7, ks = ez >> 3;
  const int by = blockIdx.y, bx = blockIdx.x;
  const int pb = abase[e], pcnt = abase[e + 1] - pb;
  if (by * 256 >= pcnt) return;
  const int g0 = ks * 32;
  const int gend = split ? (g0 + 32) : 64;
  unsigned short* eo = ks ? eout_b : eout_a;
  __shared__ char smem[131072];
  const int tid = threadIdx.x, wid = tid >> 6, lane = tid & 63;
  const int wr = wid >> 2, wc = wid & 3;
  const int rr0 = tid >> 3;
  const int kbyte = ((tid & 7) ^ (rr0 & 7)) * 16;
  const int d0 = tid * 16, d1 = d0 + 8192;
  const int aoffk0 = (wr * 64 + (lane & 15)) * 128 + (((lane >> 4) ^ (lane & 7)) * 16);
  const int aoffk1 = aoffk0 ^ 64;
  const int boffk0 = (wc * 32 + (lane & 15)) * 128 + (((lane >> 4) ^ (lane & 7)) * 16);
  const int boffk1 = boffk0 ^ 64;

  const char* Abase = (const char*)(abuf + (size_t)(pb + by * 256) * F_DIM);
  const int brB0 = ((rr0 >> 5) * 64 + (rr0 & 31));
  const char* Bbase = (const char*)(w2t + (size_t)e * H_DIM * F_DIM + (size_t)(bx * 256) * F_DIM);

#define G2_STAGE_A(g_, mh_)                                                            \
  do {                                                                                 \
    const char* s0 = Abase + (size_t)((mh_)*64 + rr0) * 8192 + (g_)*128 + kbyte;       \
    const char* s1 = Abase + (size_t)(128 + (mh_)*64 + rr0) * 8192 + (g_)*128 + kbyte; \
    char* dst = smem + (((g_)&1) * 65536) + (mh_)*16384;                               \
    gload16(s0, dst + d0); gload16(s1, dst + d1);                                      \
  } while (0)

#define G2_STAGE_B(g_, nh_)                                                            \
  do {                                                                                 \
    const char* s0 = Bbase + (size_t)(brB0 + (nh_)*32) * 8192 + (g_)*128 + kbyte;      \
    const char* s1 = Bbase + (size_t)(brB0 + 128 + (nh_)*32) * 8192 + (g_)*128 + kbyte;\
    char* dst = smem + (((g_)&1) * 65536) + 32768 + (nh_)*16384;                       \
    gload16(s0, dst + d0); gload16(s1, dst + d1);                                      \
  } while (0)

  f32x4 acc[8][4] = {};
  short8 Areg[4][2], B0reg[2][2], B1reg[2][2];

  G2_STAGE_A(g0, 0); G2_STAGE_B(g0, 1); G2_STAGE_A(g0, 1); G2_STAGE_B(g0, 0);
  G2_STAGE_A(g0 + 1, 0); G2_STAGE_B(g0 + 1, 1); G2_STAGE_A(g0 + 1, 1);
  asm volatile("s_waitcnt vmcnt(6)" ::: "memory");
  __builtin_amdgcn_sched_barrier(0);
  __builtin_amdgcn_s_barrier();

  for (int g = g0; g < gend; ++g) {
    const int slot = g & 1;
    LOAD_A(0); LOAD_B(B0reg, 0);
    if (g + 1 < gend) G2_STAGE_B(g + 1, 0);
    PHASE_TAIL(MFMA_Q(0, 0, B0reg));
    LOAD_B(B1reg, 1);
    if (g + 2 < gend) G2_STAGE_A(g + 2, 0);
    PHASE_TAIL(MFMA_Q(0, 1, B1reg));
    LOAD_A(1);
    if (g + 2 < gend) G2_STAGE_B(g + 2, 1);
    PHASE_TAIL(MFMA_Q(1, 1, B1reg));
    if (g + 2 < gend) {
      G2_STAGE_A(g + 2, 1);
      asm volatile("s_waitcnt vmcnt(6)" ::: "memory");
    } else if (g + 1 < gend) {
      asm volatile("s_waitcnt vmcnt(0)" ::: "memory");
    }
    __builtin_amdgcn_sched_barrier(0);
    PHASE_TAIL(MFMA_Q(1, 0, B0reg));
  }

  const int lcol = lane & 15;
  const int gcol0 = bx * 256 + wc * 64;
  float b2v[4];
#pragma unroll
  for (int n = 0; n < 4; ++n)
    b2v[n] = (ks == 0) ? b2[(size_t)e * H_DIM + gcol0 + n * 16 + lcol] : 0.0f;
  const float* bg_e = bgate + e * T_TOK;
#pragma unroll
  for (int m = 0; m < 8; ++m) {
    const int rl = wr * 128 + m * 16 + (lane >> 4) * 4;
#pragma unroll
    for (int j = 0; j < 4; ++j) {
      const int gm = by * 256 + rl + j;
      if (gm < pcnt) {
        const float gt = bg_e[gm];
        unsigned short* orow = eo + (size_t)(pb + gm) * H_DIM + gcol0;
#pragma unroll
        for (int n = 0; n < 4; ++n)
          orow[n * 16 + lcol] = f2bf((acc[m][n][j] + b2v[n]) * gt);
      }
    }
  }
#undef G2_STAGE_A
#undef G2_STAGE_B
}

// ---------------- combine: out[t] = sum of this token's slot rows (2 or 4), bf16 in ----------------
__global__ __launch_bounds__(256) void k_combine(const unsigned short* __restrict__ ea,
                                                 const unsigned short* __restrict__ eb,
                                                 const int* __restrict__ slotmap,
                                                 const int* __restrict__ abase,
                                                 float* __restrict__ outf, int split) {
  const int t = blockIdx.x;
  const int c = threadIdx.x;
  const int v0 = slotmap[t * 2], v1 = slotmap[t * 2 + 1];
  const size_t row0 = (size_t)(abase[v0 >> 16] + (v0 & 0xffff)) * H_DIM;
  const size_t row1 = (size_t)(abase[v1 >> 16] + (v1 & 0xffff)) * H_DIM;
  uint2 a = ((const uint2*)(ea + row0))[c];
  uint2 b = ((const uint2*)(ea + row1))[c];
  float r0 = bf2f(a.x & 0xffff) + bf2f(b.x & 0xffff);
  float r1 = bf2f(a.x >> 16)    + bf2f(b.x >> 16);
  float r2 = bf2f(a.y & 0xffff) + bf2f(b.y & 0xffff);
  float r3 = bf2f(a.y >> 16)    + bf2f(b.y >> 16);
  if (split) {
    uint2 p = ((const uint2*)(eb + row0))[c];
    uint2 q = ((const uint2*)(eb + row1))[c];
    r0 += bf2f(p.x & 0xffff) + bf2f(q.x & 0xffff);
    r1 += bf2f(p.x >> 16)    + bf2f(q.x >> 16);
    r2 += bf2f(p.y & 0xffff) + bf2f(q.y & 0xffff);
    r3 += bf2f(p.y >> 16)    + bf2f(q.y >> 16);
  }
  ((float4*)outf)[(size_t)t * 256 + c] = make_float4(r0, r1, r2, r3);
}

extern "C" void kernel_launch(void* const* d_in, const int* in_sizes, int n_in,
                              void* d_out, int out_size, void* d_ws, size_t ws_size,
                              hipStream_t stream) {
  const float* x  = (const float*)d_in[0];
  const float* Wr = (const float*)d_in[1];
  const float* br = (const float*)d_in[2];
  const float* W1 = (const float*)d_in[3];
  const float* b1 = (const float*)d_in[4];
  const float* W2 = (const float*)d_in[5];
  const float* b2 = (const float*)d_in[6];
  float* out = (float*)d_out;
  float* out_final  = out;                 // 8388608
  float* out_rw     = out + 8388608;       // 65536
  float* out_disp   = out_rw + 65536;      // 65536
  float* out_aux    = out_disp + 65536;    // 1
  float* out_logits = out_aux + 1;         // 65536

  char* ws = (char*)d_ws;
  unsigned short* xb   = (unsigned short*)(ws);                 // 16,777,216 B (dead after gemm1)
  unsigned short* w1t  = (unsigned short*)(ws + 16777216);      // 67,108,864 B (dead after gemm1)
  unsigned short* w2t  = (unsigned short*)(ws + 83886080);      // 67,108,864 B
  unsigned short* abuf = (unsigned short*)(ws + 150994944);     // 142,606,336 B (17408 rows)
  int*    bidx  = (int*)(ws + 293601280);                       // 262,144 B
  float*  bgate = (float*)(ws + 293863424);                     // 262,144 B
  int*    cnt   = (int*)(ws + 294125568);                       // 64 B
  int*    abase = (int*)(ws + 294125632);                       // 64 B
  float*  sums  = (float*)(ws + 294125696);                     // 64 B
  double* ld    = (double*)(ws + 294125824);                    // 524,288 B
  int*    slotmap = (int*)(ws + 294650112);                     // 65,536 B
  unsigned short* eout_a = (unsigned short*)(ws);               // 35.7 MB bf16, reuses xb+w1t
  unsigned short* eout_b = (unsigned short*)(ws + 35651584);    // 35.7 MB bf16, still inside xb+w1t

  const int split = 1;

  // single memset covers cnt(64) + abase(64) + sums(64)
  hipMemsetAsync(cnt, 0, 192, stream);

  k_transpose_both<<<dim3(2048, 2, 8), 256, 0, stream>>>(W1, w1t, W2, w2t);
  k_logits<<<2048, 256, 0, stream>>>(x, Wr, br, ld, out_logits, xb);
  k_decide<<<32, 256, 0, stream>>>(ld, out_rw, out_disp, cnt, bidx, bgate, sums, slotmap);
  k_prefix_aux<<<1, 256, 0, stream>>>(cnt, abase, sums, out_aux, bidx, bgate);
  k_gemm1<<<dim3(32, 24, 8), 256, 0, stream>>>(xb, w1t, b1, bidx, bgate, abase, abuf);
  k_gemm2<<<dim3(4, 32, 16), 512, 0, stream>>>(abuf, w2t, b2, bgate, abase, eout_a, eout_b, split);
  k_combine<<<8192, 256, 0, stream>>>(eout_a, eout_b, slotmap, abase, out_final, split);
}